// Round 5
// baseline (2122.982 us; speedup 1.0000x reference)
//
#include <hip/hip_runtime.h>

// GCN-VAE encoder on MI355X.
// Pipeline: CSR-build(row-sorted edges) ; XW1 = X@W1 ; h = relu(spmm(XW1)+b1) ;
//           HW23 = h@[W2|W3] ; out = spmm(HW23) + [b2|b3]  (mean,std concat)
// Workspace discipline: h is staged in d_out (same element count as the final
// output), so d_ws only needs buf0 + CSR ~= 130 MB instead of ~232 MB.

// ---------------- CSR build ----------------

__global__ __launch_bounds__(256) void hist_kernel(const int* __restrict__ row,
                                                   int* __restrict__ cnt, int e) {
  int i = blockIdx.x * blockDim.x + threadIdx.x;
  int stride = gridDim.x * blockDim.x;
  for (; i < e; i += stride) atomicAdd(&cnt[row[i]], 1);
}

// Single-block chunked exclusive scan over n counts -> row_start[0..n], row_fill copy.
__global__ __launch_bounds__(1024) void scan_kernel(const int* __restrict__ cnt,
                                                    int* __restrict__ row_start,
                                                    int* __restrict__ row_fill, int n) {
  __shared__ int carry_s;
  __shared__ int wave_sums[16];
  int tid = threadIdx.x;
  int lane = tid & 63, wid = tid >> 6;
  if (tid == 0) carry_s = 0;
  __syncthreads();
  for (int base = 0; base < n; base += 1024) {
    int i = base + tid;
    int x = (i < n) ? cnt[i] : 0;
    int v = x;
#pragma unroll
    for (int off = 1; off < 64; off <<= 1) {
      int y = __shfl_up(v, off);
      if (lane >= off) v += y;
    }
    if (lane == 63) wave_sums[wid] = v;
    __syncthreads();
    if (wid == 0) {
      int s = (lane < 16) ? wave_sums[lane] : 0;
#pragma unroll
      for (int off = 1; off < 16; off <<= 1) {
        int y = __shfl_up(s, off);
        if (lane >= off) s += y;
      }
      if (lane < 16) wave_sums[lane] = s;  // inclusive wave sums
    }
    __syncthreads();
    int wave_prefix = (wid > 0) ? wave_sums[wid - 1] : 0;
    int incl = v + wave_prefix;  // inclusive within chunk
    int carry = carry_s;
    if (i < n) {
      int rs = carry + incl - x;  // exclusive
      row_start[i] = rs;
      row_fill[i] = rs;
    }
    __syncthreads();  // everyone has read carry_s / wave_sums
    if (tid == 1023) carry_s = carry + incl;
    __syncthreads();
  }
  if (tid == 0) row_start[n] = carry_s;
}

// Pack each edge as int2 {col, bitcast(val)} -> one 8B scattered store per edge
// (half the scattered transactions vs two 4B stores; col+val share a cache line).
__global__ __launch_bounds__(256) void scatter_kernel(
    const int* __restrict__ row, const int* __restrict__ col,
    const float* __restrict__ vals, int* __restrict__ row_fill,
    int2* __restrict__ sedge, int e) {
  int i = blockIdx.x * blockDim.x + threadIdx.x;
  int stride = gridDim.x * blockDim.x;
  for (; i < e; i += stride) {
    int r = row[i];
    int pos = atomicAdd(&row_fill[r], 1);
    sedge[pos] = make_int2(col[i], __float_as_int(vals[i]));
  }
}

// ---------------- dense GEMM (fp32 vector ALU; N fixed = 256) ----------------
// C[M,256] = A[M,K] @ B. If B1 != nullptr: bn=0 -> B0 [K,128] (cols 0..127),
// bn=1 -> B1 [K,128] (cols 128..255). Else B0 is [K,256], bn selects col half.
// 256 threads, BM=128 x BN=128 tile, 8x8 micro-tile (64 acc regs, ~4 waves/SIMD).
// B fragments split at tx*4 / tx*4+64 so each 16-lane ds_read_b128 hits 16
// contiguous 16B chunks (2-way bank aliasing = free; tx*8 layout would be 4-way).
#define BM 128
#define BN 128
#define BK 16

__global__ __launch_bounds__(256) void gemm_kernel(
    const float* __restrict__ A, const float* __restrict__ B0,
    const float* __restrict__ B1, float* __restrict__ C, int M, int K) {
  __shared__ float As[BK][BM + 4];  // k-major; +4 pad
  __shared__ float Bs[BK][BN];
  int tid = threadIdx.x;
  int tx = tid & 15;   // col group: cols tx*4..+3 and 64+tx*4..+3
  int ty = tid >> 4;   // row group: rows ty*8..+7
  int bm = blockIdx.x, bn = blockIdx.y;

  const float* Bsrc;
  int bcol, ldb;
  if (B1 != nullptr) { Bsrc = (bn == 0) ? B0 : B1; bcol = 0; ldb = 128; }
  else               { Bsrc = B0; bcol = bn * 128; ldb = 256; }

  float acc[8][8] = {};
  int row0 = bm * BM;

  for (int k0 = 0; k0 < K; k0 += BK) {
    // stage A tile: 512 float4, 2 per thread, k-major into LDS
#pragma unroll
    for (int t = 0; t < 2; ++t) {
      int f4 = tid + t * 256;
      int r = f4 >> 2;   // 0..127 (row)
      int c4 = f4 & 3;   // 0..3 (float4 along K)
      int gr = row0 + r;
      if (gr >= M) gr = M - 1;  // clamp: junk rows only feed guarded stores
      float4 a = *(const float4*)&A[(size_t)gr * K + k0 + c4 * 4];
      As[c4 * 4 + 0][r] = a.x;
      As[c4 * 4 + 1][r] = a.y;
      As[c4 * 4 + 2][r] = a.z;
      As[c4 * 4 + 3][r] = a.w;
    }
    // stage B tile: 512 float4, 2 per thread (row-contiguous writes)
#pragma unroll
    for (int t = 0; t < 2; ++t) {
      int f4 = tid + t * 256;
      int r = f4 >> 5;    // 0..15 (k)
      int c4 = f4 & 31;   // 0..31 (n/4)
      float4 b = *(const float4*)&Bsrc[(size_t)(k0 + r) * ldb + bcol + c4 * 4];
      *(float4*)&Bs[r][c4 * 4] = b;
    }
    __syncthreads();
#pragma unroll
    for (int kk = 0; kk < BK; ++kk) {
      float4 a0 = *(const float4*)&As[kk][ty * 8];
      float4 a1 = *(const float4*)&As[kk][ty * 8 + 4];
      float4 b0 = *(const float4*)&Bs[kk][tx * 4];
      float4 b1 = *(const float4*)&Bs[kk][tx * 4 + 64];
      float av[8] = {a0.x, a0.y, a0.z, a0.w, a1.x, a1.y, a1.z, a1.w};
      float bv[8] = {b0.x, b0.y, b0.z, b0.w, b1.x, b1.y, b1.z, b1.w};
#pragma unroll
      for (int i = 0; i < 8; ++i)
#pragma unroll
        for (int j = 0; j < 8; ++j) acc[i][j] = fmaf(av[i], bv[j], acc[i][j]);
    }
    __syncthreads();
  }
#pragma unroll
  for (int i = 0; i < 8; ++i) {
    int gr = row0 + ty * 8 + i;
    if (gr < M) {
      float4 o0 = {acc[i][0], acc[i][1], acc[i][2], acc[i][3]};
      float4 o1 = {acc[i][4], acc[i][5], acc[i][6], acc[i][7]};
      *(float4*)&C[(size_t)gr * 256 + bn * 128 + tx * 4] = o0;
      *(float4*)&C[(size_t)gr * 256 + bn * 128 + 64 + tx * 4] = o1;
    }
  }
}

// ---------------- SpMM (CSR, wave-per-row, 256 dims = 64 lanes x float4) ----------------
// Edge metadata batch-loaded one-edge-per-lane as int2 (one coalesced 8B load
// covers a whole avg-degree-32 row), broadcast from registers via uniform-index
// __shfl. 8 independent gathers in flight to cover L3 latency (~400-600 cy).

__device__ __forceinline__ float4 fma4(float v, float4 x, float4 a) {
  a.x = fmaf(v, x.x, a.x); a.y = fmaf(v, x.y, a.y);
  a.z = fmaf(v, x.z, a.z); a.w = fmaf(v, x.w, a.w);
  return a;
}

__device__ __forceinline__ float4 spmm_row_acc(
    const float* __restrict__ X, const int2* __restrict__ sedge,
    int s, int e, int lane, int d) {
  float4 acc = make_float4(0.f, 0.f, 0.f, 0.f);
  for (int jb = s; jb < e; jb += 64) {
    int idx = jb + lane;
    int cl = 0; float vl = 0.f;
    if (idx < e) { int2 ed = sedge[idx]; cl = ed.x; vl = __int_as_float(ed.y); }
    int m = e - jb; if (m > 64) m = 64;
    int k = 0;
    for (; k + 8 <= m; k += 8) {
      int   c0 = __shfl(cl, k + 0); float v0 = __shfl(vl, k + 0);
      int   c1 = __shfl(cl, k + 1); float v1 = __shfl(vl, k + 1);
      int   c2 = __shfl(cl, k + 2); float v2 = __shfl(vl, k + 2);
      int   c3 = __shfl(cl, k + 3); float v3 = __shfl(vl, k + 3);
      int   c4 = __shfl(cl, k + 4); float v4 = __shfl(vl, k + 4);
      int   c5 = __shfl(cl, k + 5); float v5 = __shfl(vl, k + 5);
      int   c6 = __shfl(cl, k + 6); float v6 = __shfl(vl, k + 6);
      int   c7 = __shfl(cl, k + 7); float v7 = __shfl(vl, k + 7);
      float4 x0 = *(const float4*)&X[(size_t)c0 * 256 + d];
      float4 x1 = *(const float4*)&X[(size_t)c1 * 256 + d];
      float4 x2 = *(const float4*)&X[(size_t)c2 * 256 + d];
      float4 x3 = *(const float4*)&X[(size_t)c3 * 256 + d];
      float4 x4 = *(const float4*)&X[(size_t)c4 * 256 + d];
      float4 x5 = *(const float4*)&X[(size_t)c5 * 256 + d];
      float4 x6 = *(const float4*)&X[(size_t)c6 * 256 + d];
      float4 x7 = *(const float4*)&X[(size_t)c7 * 256 + d];
      acc = fma4(v0, x0, acc); acc = fma4(v1, x1, acc);
      acc = fma4(v2, x2, acc); acc = fma4(v3, x3, acc);
      acc = fma4(v4, x4, acc); acc = fma4(v5, x5, acc);
      acc = fma4(v6, x6, acc); acc = fma4(v7, x7, acc);
    }
    for (; k < m; ++k) {
      int c0 = __shfl(cl, k); float v0 = __shfl(vl, k);
      float4 x0 = *(const float4*)&X[(size_t)c0 * 256 + d];
      acc = fma4(v0, x0, acc);
    }
  }
  return acc;
}

__global__ __launch_bounds__(256) void spmm_relu_kernel(
    const float* __restrict__ X, const int* __restrict__ row_start,
    const int2* __restrict__ sedge, const float* __restrict__ bias,
    float* __restrict__ h, int n) {
  int lane = threadIdx.x & 63;
  int r = blockIdx.x * 4 + (threadIdx.x >> 6);
  if (r >= n) return;
  int s = row_start[r], e = row_start[r + 1];
  int d = lane * 4;
  float4 acc = spmm_row_acc(X, sedge, s, e, lane, d);
  float4 b = *(const float4*)&bias[d];
  acc.x = fmaxf(acc.x + b.x, 0.f);
  acc.y = fmaxf(acc.y + b.y, 0.f);
  acc.z = fmaxf(acc.z + b.z, 0.f);
  acc.w = fmaxf(acc.w + b.w, 0.f);
  *(float4*)&h[(size_t)r * 256 + d] = acc;
}

// Final SpMM: X = HW23 [n,256] (cols 0..127 = h@W2, 128..255 = h@W3).
// Writes mean (+b2) to out[0 : n*128) and std (+b3) to out[n*128 : 2*n*128).
__global__ __launch_bounds__(256) void spmm_out_kernel(
    const float* __restrict__ X, const int* __restrict__ row_start,
    const int2* __restrict__ sedge, const float* __restrict__ b2,
    const float* __restrict__ b3, float* __restrict__ out, int n) {
  int lane = threadIdx.x & 63;
  int r = blockIdx.x * 4 + (threadIdx.x >> 6);
  if (r >= n) return;
  int s = row_start[r], e = row_start[r + 1];
  int d = lane * 4;
  float4 acc = spmm_row_acc(X, sedge, s, e, lane, d);
  float4 b = (d < 128) ? *(const float4*)&b2[d] : *(const float4*)&b3[d - 128];
  acc.x += b.x; acc.y += b.y; acc.z += b.z; acc.w += b.w;
  float* dst = (d < 128) ? (out + (size_t)r * 128 + d)
                         : (out + (size_t)n * 128 + (size_t)r * 128 + (d - 128));
  *(float4*)dst = acc;
}

// ---------------- launch ----------------

extern "C" void kernel_launch(void* const* d_in, const int* in_sizes, int n_in,
                              void* d_out, int out_size, void* d_ws, size_t ws_size,
                              hipStream_t stream) {
  const float* features = (const float*)d_in[0];
  const int* edge_row   = (const int*)d_in[1];
  const int* edge_col   = (const int*)d_in[2];
  const float* edge_vals= (const float*)d_in[3];
  const float* W1 = (const float*)d_in[4];
  const float* b1 = (const float*)d_in[5];
  const float* W2 = (const float*)d_in[6];
  const float* b2 = (const float*)d_in[7];
  const float* W3 = (const float*)d_in[8];
  const float* b3 = (const float*)d_in[9];
  float* out = (float*)d_out;

  const int N = in_sizes[0] / 512;  // 100000
  const int E = in_sizes[1];        // 3200000

  // workspace layout (256B aligned), small arrays first. Total ~130 MB:
  //   cnt/row_start/row_fill ~1.2 MB, sedge 25.6 MB, buf0 102.4 MB.
  // h is staged in d_out (2*N*128 = N*256 floats), overwritten by the final spmm.
  char* ws = (char*)d_ws;
  size_t off = 0;
  auto alloc = [&](size_t bytes) -> void* {
    void* p = ws + off;
    off = (off + bytes + 255) & ~(size_t)255;
    return p;
  };
  int* cnt        = (int*)alloc((size_t)N * 4);
  int* row_start  = (int*)alloc((size_t)(N + 1) * 4);
  int* row_fill   = (int*)alloc((size_t)N * 4);
  int2* sedge     = (int2*)alloc((size_t)E * 8);
  float* buf0     = (float*)alloc((size_t)N * 256 * 4);
  float* h        = out;  // stage relu output in d_out

  // CSR build (same sparse matrix reused by both SpMMs)
  hipMemsetAsync(cnt, 0, (size_t)N * 4, stream);
  hist_kernel<<<2048, 256, 0, stream>>>(edge_row, cnt, E);
  scan_kernel<<<1, 1024, 0, stream>>>(cnt, row_start, row_fill, N);
  scatter_kernel<<<2048, 256, 0, stream>>>(edge_row, edge_col, edge_vals,
                                           row_fill, sedge, E);

  dim3 ggrid((N + BM - 1) / BM, 2);
  // XW1 = features @ W1
  gemm_kernel<<<ggrid, 256, 0, stream>>>(features, W1, nullptr, buf0, N, 512);
  // h = relu(spmm(XW1) + b1)   (h lives in d_out)
  spmm_relu_kernel<<<(N + 3) / 4, 256, 0, stream>>>(buf0, row_start, sedge, b1, h, N);
  // HW23 = h @ [W2 | W3]  (into buf0)
  gemm_kernel<<<ggrid, 256, 0, stream>>>(h, W2, W3, buf0, N, 256);
  // mean/std = spmm(HW23) + [b2|b3] -> d_out (overwrites h staging)
  spmm_out_kernel<<<(N + 3) / 4, 256, 0, stream>>>(buf0, row_start, sedge, b2, b3, out, N);
}

// Round 6
// 1316.780 us; speedup vs baseline: 1.6123x; 1.6123x over previous
//
#include <hip/hip_runtime.h>

// GCN-VAE encoder on MI355X — bf16 interior pipeline, fp32 accumulation.
// CSR-build ; Xb = bf16(X@W1) [MFMA] ; hb = bf16(relu(spmm(Xb)+b1)) ;
// Hb = bf16(hb@[W2|W3]) [MFMA] ; out = spmm(Hb) + [b2|b3]  (fp32 mean,std)

typedef __bf16 bf16x8 __attribute__((ext_vector_type(8)));
typedef float f32x4 __attribute__((ext_vector_type(4)));
typedef unsigned short us8 __attribute__((ext_vector_type(8)));

__device__ __forceinline__ unsigned short f2bf(float f) {  // RNE
  unsigned u = __float_as_uint(f);
  u += 0x7FFFu + ((u >> 16) & 1u);
  return (unsigned short)(u >> 16);
}

// ---------------- CSR build ----------------

__global__ __launch_bounds__(256) void hist_kernel(const int* __restrict__ row,
                                                   int* __restrict__ cnt, int e) {
  int i = blockIdx.x * blockDim.x + threadIdx.x;
  int stride = gridDim.x * blockDim.x;
  for (; i < e; i += stride) atomicAdd(&cnt[row[i]], 1);
}

__global__ __launch_bounds__(1024) void scan_kernel(const int* __restrict__ cnt,
                                                    int* __restrict__ row_start,
                                                    int* __restrict__ row_fill, int n) {
  __shared__ int carry_s;
  __shared__ int wave_sums[16];
  int tid = threadIdx.x;
  int lane = tid & 63, wid = tid >> 6;
  if (tid == 0) carry_s = 0;
  __syncthreads();
  for (int base = 0; base < n; base += 1024) {
    int i = base + tid;
    int x = (i < n) ? cnt[i] : 0;
    int v = x;
#pragma unroll
    for (int off = 1; off < 64; off <<= 1) {
      int y = __shfl_up(v, off);
      if (lane >= off) v += y;
    }
    if (lane == 63) wave_sums[wid] = v;
    __syncthreads();
    if (wid == 0) {
      int s = (lane < 16) ? wave_sums[lane] : 0;
#pragma unroll
      for (int off = 1; off < 16; off <<= 1) {
        int y = __shfl_up(s, off);
        if (lane >= off) s += y;
      }
      if (lane < 16) wave_sums[lane] = s;
    }
    __syncthreads();
    int wave_prefix = (wid > 0) ? wave_sums[wid - 1] : 0;
    int incl = v + wave_prefix;
    int carry = carry_s;
    if (i < n) {
      int rs = carry + incl - x;
      row_start[i] = rs;
      row_fill[i] = rs;
    }
    __syncthreads();
    if (tid == 1023) carry_s = carry + incl;
    __syncthreads();
  }
  if (tid == 0) row_start[n] = carry_s;
}

__global__ __launch_bounds__(256) void scatter_kernel(
    const int* __restrict__ row, const int* __restrict__ col,
    const float* __restrict__ vals, int* __restrict__ row_fill,
    int2* __restrict__ sedge, int e) {
  int i = blockIdx.x * blockDim.x + threadIdx.x;
  int stride = gridDim.x * blockDim.x;
  for (; i < e; i += stride) {
    int r = row[i];
    int pos = atomicAdd(&row_fill[r], 1);
    sedge[pos] = make_int2(col[i], __float_as_int(vals[i]));
  }
}

// ---------------- weight convert + transpose (tiny, once per launch) ----------------
// W1t[c][k] = bf16(W1[k][c])  (256 x 512)
// W23t[c][k]: c<128 -> bf16(W2[k][c]) ; c>=128 -> bf16(W3[k][c-128])  (256 x 256)
__global__ __launch_bounds__(256) void wt_kernel(
    const float* __restrict__ W1, const float* __restrict__ W2,
    const float* __restrict__ W3, unsigned short* __restrict__ W1t,
    unsigned short* __restrict__ W23t) {
  int c = blockIdx.x, t = threadIdx.x;
  for (int k = t; k < 512; k += 256) W1t[c * 512 + k] = f2bf(W1[k * 256 + c]);
  {
    int k = t;
    float v = (c < 128) ? W2[k * 128 + c] : W3[k * 128 + (c - 128)];
    W23t[c * 256 + k] = f2bf(v);
  }
}

// ---------------- MFMA bf16 GEMM: C[M,256] = A[M,K] @ Bt^T ----------------
// Bt is pre-transposed bf16 [256][K]. A is fp32 (converted in-register while
// staging, AF32=true) or bf16 (AF32=false). Output written bf16.
// BM=128, BN=256, BK=32; 512 thr = 8 waves (2x4), wave tile 64x64 = 4x4 MFMA
// tiles of 16x16x32. Fragment layouts: A row=lane&15, B col=lane&15,
// k=(lane>>4)*8+j ; C col=lane&15, row=(lane>>4)*4+reg (m89-verified).
// LDS rows padded to 40 ushorts (80 B): 16-lane frag reads stride 20 banks ->
// 2-way aliasing (free per m136); 16B alignment preserved (80 = 5*16).
template <bool AF32>
__global__ __launch_bounds__(512) void gemm_mfma(
    const void* __restrict__ Av, const unsigned short* __restrict__ Bt,
    unsigned short* __restrict__ Cb, int M, int K) {
  __shared__ unsigned short Al[128][40];
  __shared__ unsigned short Bl[256][40];
  int tid = threadIdx.x;
  int lane = tid & 63, wid = tid >> 6;
  int wm = wid >> 2, wn = wid & 3;
  int l15 = lane & 15, lk = lane >> 4;
  int row0 = blockIdx.x * 128;

  f32x4 acc[4][4] = {};

  int arow = tid >> 2, akq = tid & 3;  // A staging: 128 rows x 4 k-quads
  int bcol = tid >> 1, bkh = tid & 1;  // B staging: 256 cols x 2 k-halves
  int agr = row0 + arow;
  if (agr >= M) agr = M - 1;  // clamp: junk rows only feed guarded stores

  for (int k0 = 0; k0 < K; k0 += 32) {
    if constexpr (AF32) {
      const float* A32 = (const float*)Av;
      const float4* s = (const float4*)&A32[(size_t)agr * K + k0 + akq * 8];
      float4 x = s[0], y = s[1];
      us8 p;
      p[0] = f2bf(x.x); p[1] = f2bf(x.y); p[2] = f2bf(x.z); p[3] = f2bf(x.w);
      p[4] = f2bf(y.x); p[5] = f2bf(y.y); p[6] = f2bf(y.z); p[7] = f2bf(y.w);
      *(us8*)&Al[arow][akq * 8] = p;
    } else {
      const unsigned short* Ab = (const unsigned short*)Av;
      *(us8*)&Al[arow][akq * 8] = *(const us8*)&Ab[(size_t)agr * K + k0 + akq * 8];
    }
    {
      const us8* s = (const us8*)&Bt[(size_t)bcol * K + k0 + bkh * 16];
      *(us8*)&Bl[bcol][bkh * 16] = s[0];
      *(us8*)&Bl[bcol][bkh * 16 + 8] = s[1];
    }
    __syncthreads();
    bf16x8 af[4], bfr[4];
#pragma unroll
    for (int mt = 0; mt < 4; ++mt)
      af[mt] = __builtin_bit_cast(bf16x8,
          *(const us8*)&Al[wm * 64 + mt * 16 + l15][lk * 8]);
#pragma unroll
    for (int nt = 0; nt < 4; ++nt)
      bfr[nt] = __builtin_bit_cast(bf16x8,
          *(const us8*)&Bl[wn * 64 + nt * 16 + l15][lk * 8]);
#pragma unroll
    for (int mt = 0; mt < 4; ++mt)
#pragma unroll
      for (int nt = 0; nt < 4; ++nt)
        acc[mt][nt] = __builtin_amdgcn_mfma_f32_16x16x32_bf16(
            af[mt], bfr[nt], acc[mt][nt], 0, 0, 0);
    __syncthreads();
  }
#pragma unroll
  for (int mt = 0; mt < 4; ++mt) {
#pragma unroll
    for (int r = 0; r < 4; ++r) {
      int grow = row0 + wm * 64 + mt * 16 + lk * 4 + r;
      if (grow < M) {
#pragma unroll
        for (int nt = 0; nt < 4; ++nt) {
          int gcol = wn * 64 + nt * 16 + l15;
          Cb[(size_t)grow * 256 + gcol] = f2bf(acc[mt][nt][r]);
        }
      }
    }
  }
}

// ---------------- SpMM (CSR, wave-per-row, bf16 X rows = 512 B) ----------------
// 64 lanes x 4 dims (uint2 = 4 bf16 per lane per gathered row). Edge metadata
// batch-loaded one int2 per lane, broadcast via uniform-index __shfl; 8
// independent gathers in flight. fp32 accumulate.

__device__ __forceinline__ void bfma(float v, uint2 g, float4& a) {
  a.x = fmaf(v, __uint_as_float(g.x << 16), a.x);
  a.y = fmaf(v, __uint_as_float(g.x & 0xFFFF0000u), a.y);
  a.z = fmaf(v, __uint_as_float(g.y << 16), a.z);
  a.w = fmaf(v, __uint_as_float(g.y & 0xFFFF0000u), a.w);
}

__device__ __forceinline__ float4 spmm_row_acc(
    const unsigned short* __restrict__ Xb, const int2* __restrict__ sedge,
    int s, int e, int lane) {
  float4 acc = make_float4(0.f, 0.f, 0.f, 0.f);
  const char* Xc = (const char*)Xb;
  int dbyte = lane * 8;
  for (int jb = s; jb < e; jb += 64) {
    int idx = jb + lane;
    int cl = 0; float vl = 0.f;
    if (idx < e) { int2 ed = sedge[idx]; cl = ed.x; vl = __int_as_float(ed.y); }
    int m = e - jb; if (m > 64) m = 64;
    int k = 0;
    for (; k + 8 <= m; k += 8) {
      int   c0 = __shfl(cl, k + 0); float v0 = __shfl(vl, k + 0);
      int   c1 = __shfl(cl, k + 1); float v1 = __shfl(vl, k + 1);
      int   c2 = __shfl(cl, k + 2); float v2 = __shfl(vl, k + 2);
      int   c3 = __shfl(cl, k + 3); float v3 = __shfl(vl, k + 3);
      int   c4 = __shfl(cl, k + 4); float v4 = __shfl(vl, k + 4);
      int   c5 = __shfl(cl, k + 5); float v5 = __shfl(vl, k + 5);
      int   c6 = __shfl(cl, k + 6); float v6 = __shfl(vl, k + 6);
      int   c7 = __shfl(cl, k + 7); float v7 = __shfl(vl, k + 7);
      uint2 x0 = *(const uint2*)(Xc + ((size_t)c0 << 9) + dbyte);
      uint2 x1 = *(const uint2*)(Xc + ((size_t)c1 << 9) + dbyte);
      uint2 x2 = *(const uint2*)(Xc + ((size_t)c2 << 9) + dbyte);
      uint2 x3 = *(const uint2*)(Xc + ((size_t)c3 << 9) + dbyte);
      uint2 x4 = *(const uint2*)(Xc + ((size_t)c4 << 9) + dbyte);
      uint2 x5 = *(const uint2*)(Xc + ((size_t)c5 << 9) + dbyte);
      uint2 x6 = *(const uint2*)(Xc + ((size_t)c6 << 9) + dbyte);
      uint2 x7 = *(const uint2*)(Xc + ((size_t)c7 << 9) + dbyte);
      bfma(v0, x0, acc); bfma(v1, x1, acc); bfma(v2, x2, acc); bfma(v3, x3, acc);
      bfma(v4, x4, acc); bfma(v5, x5, acc); bfma(v6, x6, acc); bfma(v7, x7, acc);
    }
    for (; k < m; ++k) {
      int c0 = __shfl(cl, k); float v0 = __shfl(vl, k);
      uint2 x0 = *(const uint2*)(Xc + ((size_t)c0 << 9) + dbyte);
      bfma(v0, x0, acc);
    }
  }
  return acc;
}

// h = bf16(relu(spmm(Xb) + b1))
__global__ __launch_bounds__(256) void spmm_relu_kernel(
    const unsigned short* __restrict__ Xb, const int* __restrict__ row_start,
    const int2* __restrict__ sedge, const float* __restrict__ bias,
    unsigned short* __restrict__ hb, int n) {
  int lane = threadIdx.x & 63;
  int r = blockIdx.x * 4 + (threadIdx.x >> 6);
  if (r >= n) return;
  int s = row_start[r], e = row_start[r + 1];
  float4 acc = spmm_row_acc(Xb, sedge, s, e, lane);
  int d0 = lane * 4;
  float4 b = *(const float4*)&bias[d0];
  float ax = fmaxf(acc.x + b.x, 0.f), ay = fmaxf(acc.y + b.y, 0.f);
  float az = fmaxf(acc.z + b.z, 0.f), aw = fmaxf(acc.w + b.w, 0.f);
  uint2 o;
  o.x = (unsigned)f2bf(ax) | ((unsigned)f2bf(ay) << 16);
  o.y = (unsigned)f2bf(az) | ((unsigned)f2bf(aw) << 16);
  *(uint2*)&hb[(size_t)r * 256 + d0] = o;
}

// out = spmm(Hb) + [b2|b3]; Hb cols 0..127 = h@W2, 128..255 = h@W3.
// mean (+b2) -> out[0:n*128), std (+b3) -> out[n*128:2*n*128), fp32.
__global__ __launch_bounds__(256) void spmm_out_kernel(
    const unsigned short* __restrict__ Hb, const int* __restrict__ row_start,
    const int2* __restrict__ sedge, const float* __restrict__ b2,
    const float* __restrict__ b3, float* __restrict__ out, int n) {
  int lane = threadIdx.x & 63;
  int r = blockIdx.x * 4 + (threadIdx.x >> 6);
  if (r >= n) return;
  int s = row_start[r], e = row_start[r + 1];
  float4 acc = spmm_row_acc(Hb, sedge, s, e, lane);
  int d0 = lane * 4;
  float4 b = (d0 < 128) ? *(const float4*)&b2[d0] : *(const float4*)&b3[d0 - 128];
  acc.x += b.x; acc.y += b.y; acc.z += b.z; acc.w += b.w;
  float* dst = (d0 < 128) ? (out + (size_t)r * 128 + d0)
                          : (out + (size_t)n * 128 + (size_t)r * 128 + (d0 - 128));
  *(float4*)dst = acc;
}

// ---------------- launch ----------------

extern "C" void kernel_launch(void* const* d_in, const int* in_sizes, int n_in,
                              void* d_out, int out_size, void* d_ws, size_t ws_size,
                              hipStream_t stream) {
  const float* features = (const float*)d_in[0];
  const int* edge_row   = (const int*)d_in[1];
  const int* edge_col   = (const int*)d_in[2];
  const float* edge_vals= (const float*)d_in[3];
  const float* W1 = (const float*)d_in[4];
  const float* b1 = (const float*)d_in[5];
  const float* W2 = (const float*)d_in[6];
  const float* b2 = (const float*)d_in[7];
  const float* W3 = (const float*)d_in[8];
  const float* b3 = (const float*)d_in[9];
  float* out = (float*)d_out;

  const int N = in_sizes[0] / 512;  // 100000
  const int E = in_sizes[1];        // 3200000

  // workspace (256B-aligned), ~130 MB total (the footprint that passed):
  // cnt/rs/rf 1.2 MB, sedge 25.6 MB, W1t 0.26 MB, W23t 0.13 MB,
  // Xb 51.2 MB (gemm1 out; reused as gemm2 out), hb 51.2 MB.
  char* ws = (char*)d_ws;
  size_t off = 0;
  auto alloc = [&](size_t bytes) -> void* {
    void* p = ws + off;
    off = (off + bytes + 255) & ~(size_t)255;
    return p;
  };
  int* cnt        = (int*)alloc((size_t)N * 4);
  int* row_start  = (int*)alloc((size_t)(N + 1) * 4);
  int* row_fill   = (int*)alloc((size_t)N * 4);
  int2* sedge     = (int2*)alloc((size_t)E * 8);
  unsigned short* W1t  = (unsigned short*)alloc((size_t)256 * 512 * 2);
  unsigned short* W23t = (unsigned short*)alloc((size_t)256 * 256 * 2);
  unsigned short* Xb   = (unsigned short*)alloc((size_t)N * 256 * 2);
  unsigned short* hb   = (unsigned short*)alloc((size_t)N * 256 * 2);

  // CSR build + weight prep
  hipMemsetAsync(cnt, 0, (size_t)N * 4, stream);
  wt_kernel<<<256, 256, 0, stream>>>(W1, W2, W3, W1t, W23t);
  hist_kernel<<<2048, 256, 0, stream>>>(edge_row, cnt, E);
  scan_kernel<<<1, 1024, 0, stream>>>(cnt, row_start, row_fill, N);
  scatter_kernel<<<2048, 256, 0, stream>>>(edge_row, edge_col, edge_vals,
                                           row_fill, sedge, E);

  int ggrid = (N + 127) / 128;
  // Xb = bf16(features @ W1)
  gemm_mfma<true><<<ggrid, 512, 0, stream>>>(features, W1t, Xb, N, 512);
  // hb = bf16(relu(spmm(Xb) + b1))
  spmm_relu_kernel<<<(N + 3) / 4, 256, 0, stream>>>(Xb, row_start, sedge, b1, hb, N);
  // Xb <- bf16(hb @ [W2|W3])   (reuse)
  gemm_mfma<false><<<ggrid, 512, 0, stream>>>(hb, W23t, Xb, N, 256);
  // out = spmm(Xb) + [b2|b3]
  spmm_out_kernel<<<(N + 3) / 4, 256, 0, stream>>>(Xb, row_start, sedge, b2, b3, out, N);
}